// Round 2
// 2007.770 us; speedup vs baseline: 1.0689x; 1.0689x over previous
//
#include <hip/hip_runtime.h>

#define DEV __device__ __forceinline__

constexpr int Bb = 2, Ls = 2048, Dd = 512, Vv = 50257, NLl = 12, Kk = 5;
constexpr int Aa = Dd / 4;   // 128
constexpr int Hh = Dd / 4;   // 128
constexpr int Mm = Bb * Ls;  // 4096
constexpr float EPSf = 1e-6f;
constexpr int NC = 64, Lc = Ls / NC;  // scan chunks: 64 x 32

typedef __bf16 bf16x8 __attribute__((ext_vector_type(8)));
typedef float f32x4 __attribute__((ext_vector_type(4)));

typedef __attribute__((address_space(1))) void GVoid;
typedef __attribute__((address_space(3))) void LVoid;

DEV void gl_lds16(const void* g, void* l) {
  __builtin_amdgcn_global_load_lds((GVoid*)g, (LVoid*)l, 16, 0, 0);
}

// counted vmcnt wait (T4): literal-immediate inline asm, memory clobber so the
// compiler cannot move gl_lds issues or LDS reads across it.
template <int N> DEV void waitvm() {
  if constexpr (N == 0) asm volatile("s_waitcnt vmcnt(0)" ::: "memory");
  else if constexpr (N == 3) asm volatile("s_waitcnt vmcnt(3)" ::: "memory");
  else if constexpr (N == 4) asm volatile("s_waitcnt vmcnt(4)" ::: "memory");
  else if constexpr (N == 6) asm volatile("s_waitcnt vmcnt(6)" ::: "memory");
  else if constexpr (N == 8) asm volatile("s_waitcnt vmcnt(8)" ::: "memory");
  else static_assert(N == 0, "unsupported vmcnt");
}
DEV void sbar() { __builtin_amdgcn_s_barrier(); }
DEV void schedb() { __builtin_amdgcn_sched_barrier(0); }

DEV unsigned short f2bf(float f) {
  unsigned u = __builtin_bit_cast(unsigned, f);
  u += 0x7fffu + ((u >> 16) & 1u);
  return (unsigned short)(u >> 16);
}

// ---------------- batched fp32 -> bf16 convert ----------------
struct CvtArgs {
  const float* src[6];
  unsigned short* dst[6];
  int n4[6];
};

__global__ __launch_bounds__(256) void k_cvt_multi(CvtArgs a, int total4) {
  int i = blockIdx.x * 256 + threadIdx.x;
  if (i >= total4) return;
#pragma unroll
  for (int s = 0; s < 6; s++) {
    if (i < a.n4[s]) {
      float4 v = ((const float4*)a.src[s])[i];
      ushort4 o;
      o.x = f2bf(v.x); o.y = f2bf(v.y); o.z = f2bf(v.z); o.w = f2bf(v.w);
      ((ushort4*)a.dst[s])[i] = o;
      return;
    }
    i -= a.n4[s];
  }
}

// ---------------- embedding gather + RoPE ----------------
__global__ __launch_bounds__(256) void k_embed(const int* __restrict__ tok,
                                               const float* __restrict__ emb,
                                               float* __restrict__ X) {
  int m = blockIdx.x;
  int l = m & (Ls - 1);
  int t = tok[m];
  const float* er = emb + (size_t)t * Dd;
  int d = threadIdx.x;
  float inv = powf(10000.f, -(float)d * (1.f / 256.f));
  float ang = (float)l * inv;
  float s, c;
  sincosf(ang, &s, &c);
  float x1 = er[d], x2 = er[d + 256];
  X[(size_t)m * Dd + d]       = x1 * c - x2 * s;
  X[(size_t)m * Dd + d + 256] = x2 * c + x1 * s;
}

// ---------------- RMSNorm (row per block) ----------------
template <bool BF16OUT>
__global__ __launch_bounds__(256) void k_rms(const float* __restrict__ X,
                                             const float* __restrict__ w,
                                             float* __restrict__ outF,
                                             unsigned short* __restrict__ outB) {
  int m = blockIdx.x;
  const float* xr = X + (size_t)m * Dd;
  int t = threadIdx.x;
  float2 v = ((const float2*)xr)[t];
  float ss = v.x * v.x + v.y * v.y;
  for (int off = 32; off; off >>= 1) ss += __shfl_down(ss, off, 64);
  __shared__ float red[4];
  int lane = t & 63, wid = t >> 6;
  if (!lane) red[wid] = ss;
  __syncthreads();
  float tot = red[0] + red[1] + red[2] + red[3];
  float inv = rsqrtf(tot * (1.f / Dd) + EPSf);
  float2 wv = ((const float2*)w)[t];
  float o0 = wv.x * v.x * inv, o1 = wv.y * v.y * inv;
  if (BF16OUT) {
    ushort2 uv; uv.x = f2bf(o0); uv.y = f2bf(o1);
    ((ushort2*)(outB + (size_t)m * Dd))[t] = uv;
  } else {
    float2 ov; ov.x = o0; ov.y = o1;
    ((float2*)(outF + (size_t)m * Dd))[t] = ov;
  }
}

// ---------------- dilated depthwise conv (K=5), writes bf16 ----------------
__global__ __launch_bounds__(256) void k_dwconv(const float* __restrict__ XN,
                                                const float* __restrict__ w,
                                                const float* __restrict__ bias,
                                                unsigned short* __restrict__ CB, int dil) {
  int idx = blockIdx.x * 256 + threadIdx.x;
  int d = idx & (Dd - 1);
  int ml = idx >> 9;
  int l = ml & (Ls - 1);
  float acc = bias[d];
#pragma unroll
  for (int k = 0; k < 5; k++) {
    int ll = l + (k - 2) * dil;
    if (ll >= 0 && ll < Ls) acc += w[d * 5 + k] * XN[(size_t)(ml + (ll - l)) * Dd + d];
  }
  CB[idx] = f2bf(acc);
}

// ---------------- recurrence: chunked scan ----------------
__global__ __launch_bounds__(128) void k_scanA(const float* __restrict__ XN,
                                               const float* __restrict__ al,
                                               const float* __restrict__ be,
                                               float* __restrict__ X2, float* __restrict__ S) {
  int b = blockIdx.x >> 6, c = blockIdx.x & 63;
  int a = threadIdx.x;
  float av = al[a], bv = be[a], h = 0.f;
  size_t base = ((size_t)b * Ls + c * Lc) * Dd + a;
#pragma unroll 4
  for (int j = 0; j < Lc; j++) {
    float xv = XN[base + (size_t)j * Dd];
    h = av * h + bv * xv;
    X2[base + (size_t)j * Dd] = h;  // local scan (temp)
  }
  S[(b * NC + c) * Aa + a] = h;
}

// chunk-carry scan + alpha-power table (alP[a*Lc+j] = al[a]^(j+1))
__global__ __launch_bounds__(256) void k_scanB(const float* __restrict__ al,
                                               const float* __restrict__ S,
                                               float* __restrict__ Cin,
                                               float* __restrict__ alP) {
  int t = threadIdx.x;
  int b = t >> 7, a = t & 127;
  float av = al[a];
  float pw = 1.f;
#pragma unroll
  for (int j = 0; j < Lc; j++) {
    pw *= av;
    if (b == 0) alP[a * Lc + j] = pw;
  }
  float aL = pw;  // al^Lc
  float carry = 0.f;
  for (int c = 0; c < NC; c++) {
    Cin[(b * NC + c) * Aa + a] = carry;
    carry = aL * carry + S[(b * NC + c) * Aa + a];
  }
}

// ---------------- bf16 NT GEMM: A(MxK) row-major, B(NxK) row-major ----------------
// Double-buffered LDS, raw s_barrier + counted vmcnt (loads stay in flight across
// barriers — T4), s_setprio around MFMA cluster (T5), XOR-swizzled LDS (T2).
enum : int { EPI_PCONV = 0, EPI_GATE = 1, EPI_GELU = 2, EPI_UP = 3, EPI_OUT = 4 };

template <int BM, int BN, int EPI, bool DUALB, bool MASKN, bool SWAP>
__global__ __launch_bounds__(256) void k_gemm(const unsigned short* __restrict__ A,
                                              const unsigned short* __restrict__ B1,
                                              const unsigned short* __restrict__ B2,
                                              const float* __restrict__ bias1,
                                              const float* __restrict__ bias2,
                                              const float* __restrict__ add1,
                                              const float* __restrict__ add2,
                                              const float* __restrict__ aux1,
                                              const float* __restrict__ aux2,
                                              float* __restrict__ outF,
                                              unsigned short* __restrict__ outB,
                                              int K, int ldc, int nmax) {
  constexpr int NB = DUALB ? 2 : 1;
  constexpr int TILE = (BM + NB * BN) * 64;           // shorts per K-tile buffer
  constexpr int ARND = BM * 8 / 256, BRND = BN * 8 / 256;
  constexpr int NLD = ARND + NB * BRND;               // gl_lds per thread per tile
  __shared__ unsigned short smem[2 * TILE];

  const int tid = threadIdx.x, lane = tid & 63, wid = tid >> 6;
  const int bm = (SWAP ? blockIdx.x : blockIdx.y) * BM;
  const int bn = (SWAP ? blockIdx.y : blockIdx.x) * BN;
  constexpr int TM = BM / 32, TN = BN / 32;
  const int wm = (wid & 1) * (BM / 2), wn = (wid >> 1) * (BN / 2);
  const int q = lane >> 4, mr = lane & 15;

  f32x4 acc1[TM][TN] = {};
  f32x4 acc2[TM][TN] = {};

  const int NT = K >> 6;  // all users have NT >= 2

  auto stage = [&](int kb, int buf) {
    unsigned short* smA = smem + buf * TILE;
    unsigned short* smB1 = smA + BM * 64;
    unsigned short* smB2 = DUALB ? smB1 + BN * 64 : smB1;
#pragma unroll
    for (int bch = 0; bch < ARND; ++bch) {
      int s = bch * 256 + wid * 64 + lane;
      int r = s >> 3, c = (s & 7) ^ (r & 7);
      gl_lds16(A + (size_t)(bm + r) * K + kb + c * 8, smA + (size_t)(bch * 256 + wid * 64) * 8);
    }
#pragma unroll
    for (int bch = 0; bch < BRND; ++bch) {
      int s = bch * 256 + wid * 64 + lane;
      int r = s >> 3, c = (s & 7) ^ (r & 7);
      int row = bn + r;
      if (MASKN) row = min(row, nmax - 1);
      gl_lds16(B1 + (size_t)row * K + kb + c * 8, smB1 + (size_t)(bch * 256 + wid * 64) * 8);
      if constexpr (DUALB)
        gl_lds16(B2 + (size_t)row * K + kb + c * 8, smB2 + (size_t)(bch * 256 + wid * 64) * 8);
    }
  };

  // prologue: tiles 0 and 1 in flight; wait tile 0 only.
  stage(0, 0);
  stage(64, 1);
  waitvm<NLD>();
  sbar();
  schedb();

  for (int t = 0;; ++t) {
    const unsigned short* smA = smem + (t & 1) * TILE;
    const unsigned short* smB1 = smA + BM * 64;
    const unsigned short* smB2 = DUALB ? smB1 + BN * 64 : smB1;
#pragma unroll
    for (int ks = 0; ks < 2; ++ks) {
      bf16x8 af[TM], bfa[TN], bfb[TN];
#pragma unroll
      for (int i = 0; i < TM; i++) {
        int r = wm + i * 16 + mr, c = ks * 4 + q;
        af[i] = *(const bf16x8*)(smA + (r * 8 + (c ^ (r & 7))) * 8);
      }
#pragma unroll
      for (int j = 0; j < TN; j++) {
        int r = wn + j * 16 + mr, c = ks * 4 + q;
        int slot = r * 8 + (c ^ (r & 7));
        bfa[j] = *(const bf16x8*)(smB1 + slot * 8);
        if constexpr (DUALB) bfb[j] = *(const bf16x8*)(smB2 + slot * 8);
      }
      __builtin_amdgcn_s_setprio(1);
#pragma unroll
      for (int i = 0; i < TM; i++)
#pragma unroll
        for (int j = 0; j < TN; j++) {
          acc1[i][j] = __builtin_amdgcn_mfma_f32_16x16x32_bf16(af[i], bfa[j], acc1[i][j], 0, 0, 0);
          if constexpr (DUALB)
            acc2[i][j] = __builtin_amdgcn_mfma_f32_16x16x32_bf16(af[i], bfb[j], acc2[i][j], 0, 0, 0);
        }
      __builtin_amdgcn_s_setprio(0);
    }
    if (t == NT - 1) break;
    schedb();
    sbar();  // all waves done reading buf[t&1]; safe to overwrite
    if (t + 2 < NT) {
      stage((t + 2) * 64, t & 1);
      waitvm<NLD>();   // tile t+1 complete; tile t+2 still in flight
    } else {
      waitvm<0>();     // last prefetched tile: full drain
    }
    sbar();
    schedb();
  }

  // epilogue: D[row=q*4+reg][col=lane&15]
#pragma unroll
  for (int i = 0; i < TM; i++) {
#pragma unroll
    for (int j = 0; j < TN; j++) {
      int col = bn + wn + j * 16 + mr;
      if (MASKN && col >= nmax) continue;
#pragma unroll
      for (int r = 0; r < 4; r++) {
        int row = bm + wm + i * 16 + q * 4 + r;
        size_t o = (size_t)row * ldc + col;
        float a1 = acc1[i][j][r];
        if constexpr (EPI == EPI_OUT) {
          outF[o] = a1;
        } else if constexpr (EPI == EPI_PCONV) {
          // xc (=a1+bias) + xr; xr = local_scan + al^(j+1)*chunk_carry for d<Aa, else xn
          float y = a1 + bias1[col];
          float v;
          if (col < Aa) {
            int l = row & (Ls - 1);
            int b = row >> 11;
            int jj = l & (Lc - 1), c = l >> 5;  // Lc=32
            float h = add1[o] + aux2[col * Lc + jj] * aux1[(b * NC + c) * Aa + col];
            v = y + h;
          } else {
            v = y + add2[o];
          }
          outF[o] = v;
          outB[o] = f2bf(v);
        } else if constexpr (EPI == EPI_GELU) {
          float g = a1 + bias1[col];
          float h = 0.5f * g * (1.f + erff(g * 0.70710678118654752f));
          outB[o] = f2bf(h);
        } else if constexpr (EPI == EPI_GATE) {
          float g1 = a1 + bias1[col];
          float g2 = acc2[i][j][r] + bias2[col];
          float sg = 1.f / (1.f + expf(-g1));
          float v = add1[o] + sg * tanhf(g2);
          outF[o] = v;
          outB[o] = f2bf(v);
        } else if constexpr (EPI == EPI_UP) {
          float v = a1 + bias1[col] + add1[o] + add2[o];
          outF[o] = v;
        }
      }
    }
  }
}

// ---------------- logits GEMM: 256x256 tile, 8 waves, BK=64, 128KiB LDS ----------------
// Same counted-vmcnt double-buffer pipeline; 64 MFMA/wave per K-step.
__global__ __launch_bounds__(512, 2) void k_gemm256(const unsigned short* __restrict__ A,
                                                    const unsigned short* __restrict__ B,
                                                    float* __restrict__ out,
                                                    int K, int nmax) {
  constexpr int TILE = 2 * 256 * 64;  // shorts: A(256x64) + B(256x64)
  __shared__ unsigned short smem[2 * TILE];  // 128 KiB (legal on gfx950: 160 KiB/CU)
  const int tid = threadIdx.x, lane = tid & 63, wid = tid >> 6;
  const int bm = blockIdx.x * 256, bn = blockIdx.y * 256;
  const int wm = (wid >> 2) * 128, wn = (wid & 3) * 64;  // 2x4 wave grid, 128x64 per wave
  const int q = lane >> 4, mr = lane & 15;

  f32x4 acc[8][4] = {};
  const int NT = K >> 6;  // 8 for K=512

  auto stage = [&](int kb, int buf) {
    unsigned short* smA = smem + buf * TILE;
    unsigned short* smB = smA + 256 * 64;
#pragma unroll
    for (int bch = 0; bch < 4; ++bch) {
      int s = bch * 512 + wid * 64 + lane;
      int r = s >> 3, c = (s & 7) ^ (r & 7);
      gl_lds16(A + (size_t)(bm + r) * K + kb + c * 8, smA + (size_t)(bch * 512 + wid * 64) * 8);
    }
#pragma unroll
    for (int bch = 0; bch < 4; ++bch) {
      int s = bch * 512 + wid * 64 + lane;
      int r = s >> 3, c = (s & 7) ^ (r & 7);
      int row = min(bn + r, nmax - 1);
      gl_lds16(B + (size_t)row * K + kb + c * 8, smB + (size_t)(bch * 512 + wid * 64) * 8);
    }
  };

  stage(0, 0);
  stage(64, 1);
  waitvm<8>();
  sbar();
  schedb();

  for (int t = 0;; ++t) {
    const unsigned short* smA = smem + (t & 1) * TILE;
    const unsigned short* smB = smA + 256 * 64;
#pragma unroll
    for (int ks = 0; ks < 2; ++ks) {
      bf16x8 af[8], bf[4];
#pragma unroll
      for (int i = 0; i < 8; i++) {
        int r = wm + i * 16 + mr, c = ks * 4 + q;
        af[i] = *(const bf16x8*)(smA + (r * 8 + (c ^ (r & 7))) * 8);
      }
#pragma unroll
      for (int j = 0; j < 4; j++) {
        int r = wn + j * 16 + mr, c = ks * 4 + q;
        bf[j] = *(const bf16x8*)(smB + (r * 8 + (c ^ (r & 7))) * 8);
      }
      __builtin_amdgcn_s_setprio(1);
#pragma unroll
      for (int i = 0; i < 8; i++)
#pragma unroll
        for (int j = 0; j < 4; j++)
          acc[i][j] = __builtin_amdgcn_mfma_f32_16x16x32_bf16(af[i], bf[j], acc[i][j], 0, 0, 0);
      __builtin_amdgcn_s_setprio(0);
    }
    if (t == NT - 1) break;
    schedb();
    sbar();
    if (t + 2 < NT) {
      stage((t + 2) * 64, t & 1);
      waitvm<8>();
    } else {
      waitvm<0>();
    }
    sbar();
    schedb();
  }

#pragma unroll
  for (int i = 0; i < 8; i++) {
#pragma unroll
    for (int j = 0; j < 4; j++) {
      int col = bn + wn + j * 16 + mr;
      if (col >= nmax) continue;
      size_t o = (size_t)(bm + wm + i * 16 + q * 4) * nmax + col;
#pragma unroll
      for (int r = 0; r < 4; r++) out[o + (size_t)r * nmax] = acc[i][j][r];
    }
  }
}

extern "C" void kernel_launch(void* const* d_in, const int* in_sizes, int n_in,
                              void* d_out, int out_size, void* d_ws, size_t ws_size,
                              hipStream_t stream) {
  const int*   tokens  = (const int*)d_in[0];
  const float* emb     = (const float*)d_in[1];
  const float* norm_w  = (const float*)d_in[2];
  const float* dconv_w = (const float*)d_in[3];
  const float* dconv_b = (const float*)d_in[4];
  const float* pconv_w = (const float*)d_in[5];
  const float* pconv_b = (const float*)d_in[6];
  const float* alpha   = (const float*)d_in[7];
  const float* beta    = (const float*)d_in[8];
  const float* w1      = (const float*)d_in[9];
  const float* b1      = (const float*)d_in[10];
  const float* w2      = (const float*)d_in[11];
  const float* b2      = (const float*)d_in[12];
  const float* down_w  = (const float*)d_in[13];
  const float* down_b  = (const float*)d_in[14];
  const float* up_w    = (const float*)d_in[15];
  const float* up_b    = (const float*)d_in[16];
  const float* fnw     = (const float*)d_in[17];
  float* out = (float*)d_out;

  char* p = (char*)d_ws;
  auto alloc = [&](size_t bytes) {
    void* r = p;
    p += (bytes + 255) & ~(size_t)255;
    return r;
  };
  float* X   = (float*)alloc((size_t)Mm * Dd * 4);
  float* XN  = (float*)alloc((size_t)Mm * Dd * 4);
  float* X2  = (float*)alloc((size_t)Mm * Dd * 4);
  float* X3  = (float*)alloc((size_t)Mm * Dd * 4);
  unsigned short* CB  = (unsigned short*)alloc((size_t)Mm * Dd * 2);
  unsigned short* X2B = (unsigned short*)alloc((size_t)Mm * Dd * 2);
  unsigned short* X3B = (unsigned short*)alloc((size_t)Mm * Dd * 2);
  unsigned short* XFB = (unsigned short*)alloc((size_t)Mm * Dd * 2);
  unsigned short* HB  = (unsigned short*)alloc((size_t)Mm * Hh * 2);
  float* S   = (float*)alloc((size_t)Bb * NC * Aa * 4);
  float* Cin = (float*)alloc((size_t)Bb * NC * Aa * 4);
  float* alP = (float*)alloc((size_t)Aa * Lc * 4);
  unsigned short* embB = (unsigned short*)alloc((size_t)Vv * Dd * 2);
  unsigned short* pwB  = (unsigned short*)alloc((size_t)NLl * Dd * Dd * 2);
  unsigned short* w1B  = (unsigned short*)alloc((size_t)NLl * Dd * Dd * 2);
  unsigned short* w2B  = (unsigned short*)alloc((size_t)NLl * Dd * Dd * 2);
  unsigned short* dwB  = (unsigned short*)alloc((size_t)NLl * Hh * Dd * 2);
  unsigned short* upB  = (unsigned short*)alloc((size_t)NLl * Dd * Hh * 2);

  // batched weight conversion (one launch)
  CvtArgs ca;
  ca.src[0] = emb;     ca.dst[0] = embB; ca.n4[0] = (Vv * Dd) / 4;
  ca.src[1] = pconv_w; ca.dst[1] = pwB;  ca.n4[1] = (NLl * Dd * Dd) / 4;
  ca.src[2] = w1;      ca.dst[2] = w1B;  ca.n4[2] = (NLl * Dd * Dd) / 4;
  ca.src[3] = w2;      ca.dst[3] = w2B;  ca.n4[3] = (NLl * Dd * Dd) / 4;
  ca.src[4] = down_w;  ca.dst[4] = dwB;  ca.n4[4] = (NLl * Hh * Dd) / 4;
  ca.src[5] = up_w;    ca.dst[5] = upB;  ca.n4[5] = (NLl * Dd * Hh) / 4;
  int total4 = ca.n4[0] + ca.n4[1] + ca.n4[2] + ca.n4[3] + ca.n4[4] + ca.n4[5];
  k_cvt_multi<<<(total4 + 255) / 256, 256, 0, stream>>>(ca, total4);

  k_embed<<<Mm, 256, 0, stream>>>(tokens, emb, X);

  for (int i = 0; i < NLl; i++) {
    int dil = 1 << (i % 3);
    k_rms<false><<<Mm, 256, 0, stream>>>(X, norm_w + i * Dd, XN, nullptr);
    k_dwconv<<<Mm * Dd / 256, 256, 0, stream>>>(XN, dconv_w + (size_t)i * Dd * Kk,
                                                dconv_b + i * Dd, CB, dil);
    k_scanA<<<Bb * NC, 128, 0, stream>>>(XN, alpha + i * Aa, beta + i * Aa, X2, S);
    k_scanB<<<1, 256, 0, stream>>>(alpha + i * Aa, S, Cin, alP);
    // pconv GEMM with fused recurrence-combine epilogue (writes X2/X2B directly)
    k_gemm<64, 64, EPI_PCONV, false, false, false><<<dim3(8, 64), 256, 0, stream>>>(
        CB, pwB + (size_t)i * Dd * Dd, nullptr, pconv_b + i * Dd, nullptr,
        X2, XN, Cin, alP, X2, X2B, Dd, Dd, 0);
    k_gemm<64, 64, EPI_GATE, true, false, false><<<dim3(8, 64), 256, 0, stream>>>(
        X2B, w1B + (size_t)i * Dd * Dd, w2B + (size_t)i * Dd * Dd, b1 + i * Dd, b2 + i * Dd,
        X2, nullptr, nullptr, nullptr, X3, X3B, Dd, Dd, 0);
    k_gemm<32, 64, EPI_GELU, false, false, false><<<dim3(2, 128), 256, 0, stream>>>(
        X3B, dwB + (size_t)i * Hh * Dd, nullptr, down_b + i * Hh, nullptr,
        nullptr, nullptr, nullptr, nullptr, nullptr, HB, Dd, Hh, 0);
    k_gemm<64, 64, EPI_UP, false, false, false><<<dim3(8, 64), 256, 0, stream>>>(
        HB, upB + (size_t)i * Dd * Hh, nullptr, up_b + i * Dd, nullptr,
        X3, X, nullptr, nullptr, X, nullptr, Hh, Dd, 0);
  }

  k_rms<true><<<Mm, 256, 0, stream>>>(X, fnw, nullptr, XFB);
  // logits: 256x256 8-wave pipelined GEMM; blockIdx.x = M-dim so the 16 M-blocks
  // of one N-tile run consecutively and share the B tile (A stays L2-resident).
  k_gemm256<<<dim3(Mm / 256, (Vv + 255) / 256), 512, 0, stream>>>(XFB, embB, out, Dd, Vv);
}